// Round 1
// baseline (703.420 us; speedup 1.0000x reference)
//
#include <hip/hip_runtime.h>
#include <math.h>

#define L_ 4096
#define NROW 8192   // B*L
#define NUNIT 65536 // B*L*H

__device__ __forceinline__ float sigmoidf_(float x) { return 1.f / (1.f + __expf(-x)); }
__device__ __forceinline__ float siluf_(float x) { return x * sigmoidf_(x); }

// ---------------------------------------------------------------------------
// GEMM (NT): out[n,j] = epi( sum_c A[n,c]*W[j,c] + bias[j] )
// A: M x Kc row-major (lda), W: N x Kc row-major (ld = Kc)
// EPI 0: silu.  EPI 1: gate-merge: t=acc+bias; g=sigmoid(silu(t));
//        out = g*vex[n,j] + (1-g)*oex[n,j]
// ---------------------------------------------------------------------------
template<int EPI>
__global__ __launch_bounds__(256) void gemm_nt(
    const float* __restrict__ A, int lda,
    const float* __restrict__ W,
    const float* __restrict__ bias,
    float* __restrict__ out, int ldo,
    int M, int N, int Kc,
    const float* __restrict__ vex, int ldv,
    const float* __restrict__ oex, int ldoe)
{
    __shared__ float As[16][65];
    __shared__ float Ws[16][65];

    const int bm = blockIdx.y * 64;
    const int bn = blockIdx.x * 64;
    const int tid = threadIdx.x;
    const int tx = tid & 15;
    const int ty = tid >> 4;

    const int lrow = tid >> 2;        // 0..63
    const int lk4  = (tid & 3) * 4;   // 0,4,8,12

    float acc[4][4] = {};

    for (int k0 = 0; k0 < Kc; k0 += 16) {
        {
            int r = bm + lrow;
            float4 va = make_float4(0.f, 0.f, 0.f, 0.f);
            if (r < M) va = *(const float4*)(A + (size_t)r * lda + k0 + lk4);
            As[lk4 + 0][lrow] = va.x; As[lk4 + 1][lrow] = va.y;
            As[lk4 + 2][lrow] = va.z; As[lk4 + 3][lrow] = va.w;
        }
        {
            int r = bn + lrow;
            float4 vw = make_float4(0.f, 0.f, 0.f, 0.f);
            if (r < N) vw = *(const float4*)(W + (size_t)r * Kc + k0 + lk4);
            Ws[lk4 + 0][lrow] = vw.x; Ws[lk4 + 1][lrow] = vw.y;
            Ws[lk4 + 2][lrow] = vw.z; Ws[lk4 + 3][lrow] = vw.w;
        }
        __syncthreads();
        #pragma unroll
        for (int kk = 0; kk < 16; ++kk) {
            float a[4], b[4];
            #pragma unroll
            for (int i = 0; i < 4; ++i) a[i] = As[kk][ty * 4 + i];
            #pragma unroll
            for (int j = 0; j < 4; ++j) b[j] = Ws[kk][tx * 4 + j];
            #pragma unroll
            for (int i = 0; i < 4; ++i)
                #pragma unroll
                for (int j = 0; j < 4; ++j)
                    acc[i][j] += a[i] * b[j];
        }
        __syncthreads();
    }

    #pragma unroll
    for (int i = 0; i < 4; ++i) {
        int n = bm + ty * 4 + i;
        if (n >= M) continue;
        #pragma unroll
        for (int j = 0; j < 4; ++j) {
            int c = bn + tx * 4 + j;
            if (c >= N) continue;
            float t = acc[i][j] + (bias ? bias[c] : 0.f);
            float res;
            if (EPI == 0) {
                res = siluf_(t);
            } else {
                float g = sigmoidf_(siluf_(t));
                float vv = vex[(size_t)n * ldv + c];
                float oo = oex[(size_t)n * ldoe + c];
                res = g * vv + (1.f - g) * oo;
            }
            out[(size_t)n * ldo + c] = res;
        }
    }
}

// ---------------------------------------------------------------------------
// Per-(b,l,h) RMSNorm over D=64 + RoPE.  NOTE: reference's apply_rope uses
// x.shape[-2] == H as the position axis, so pos = h (0..7), NOT l.
// In-place. rowStride: 512 for q buffer, 1024 for kv buffer (k part).
// ---------------------------------------------------------------------------
__global__ __launch_bounds__(256) void rms_rope(
    float* __restrict__ buf, const float* __restrict__ w, int rowStride)
{
    int u = blockIdx.x * 4 + (threadIdx.x >> 6);   // unit = n*8 + h
    int lane = threadIdx.x & 63;
    int n = u >> 3;
    int h = u & 7;
    size_t off = (size_t)n * rowStride + h * 64 + lane;
    float x = buf[off];
    float ss = x * x;
    #pragma unroll
    for (int m = 32; m; m >>= 1) ss += __shfl_xor(ss, m, 64);
    float inv = rsqrtf(ss * (1.f / 64.f) + 1e-6f);
    float y = x * inv * w[lane];
    // rope with pos = h
    float p = __shfl_xor(y, 32, 64);
    int i = lane & 31;
    float freq = powf(10000.f, -(float)i / 32.f);
    float ang = (float)h * freq;
    float s, c;
    sincosf(ang, &s, &c);
    float r = (lane < 32) ? (y * c - p * s) : (p * s + y * c);
    buf[off] = r;
}

// ---------------------------------------------------------------------------
// Windowed attention: one wave per (b,l,h).
// q4: [NROW,512]; kv: [NROW,1024] (k = cols 0..511 roped, v = cols 512..1023)
// wp: [NROW,16]; out: [NROW,512]
// ---------------------------------------------------------------------------
__global__ __launch_bounds__(256) void attn_kernel(
    const float* __restrict__ q4,
    const float* __restrict__ kv,
    const float* __restrict__ wp,
    float* __restrict__ out)
{
    __shared__ float sh_q[4][64];
    __shared__ float sh_attn[4][64];

    const int wid = threadIdx.x >> 6;
    const int lane = threadIdx.x & 63;
    const int u = blockIdx.x * 4 + wid;       // (b*L+l)*8 + h
    const int n = u >> 3;                     // b*L + l
    const int h = u & 7;
    const int l = n & (L_ - 1);

    sh_q[wid][lane] = q4[(size_t)n * 512 + h * 64 + lane];

    float wpw = wp[(size_t)n * 16 + h];
    float wps = wp[(size_t)n * 16 + 8 + h];
    float width = 24.f * sigmoidf_(wpw) + 0.5f;
    float sharp = 9.5f * sigmoidf_(wps) + 0.5f;
    __syncthreads();

    // scores: lane = window index k
    float s = -INFINITY;
    if (lane < 49) {
        float rel = fabsf((float)lane - 24.f);
        float mask = sigmoidf_((width - rel) * sharp);
        float dot = 0.f;
        int lk = l + lane - 24;
        if (lk >= 0 && lk < L_) {
            const float4* kp = (const float4*)(kv + ((size_t)(n - l + lk)) * 1024 + h * 64);
            #pragma unroll
            for (int d4 = 0; d4 < 16; ++d4) {
                float4 kq = kp[d4];
                dot += sh_q[wid][d4 * 4 + 0] * kq.x + sh_q[wid][d4 * 4 + 1] * kq.y
                     + sh_q[wid][d4 * 4 + 2] * kq.z + sh_q[wid][d4 * 4 + 3] * kq.w;
            }
        }
        s = dot * 0.125f - (1.f - mask) * 10000.f;
    }
    // softmax across wave (lanes >= 49 contribute exp(-inf)=0)
    float mx = s;
    #pragma unroll
    for (int m = 32; m; m >>= 1) mx = fmaxf(mx, __shfl_xor(mx, m, 64));
    float e = __expf(s - mx);
    float sum = e;
    #pragma unroll
    for (int m = 32; m; m >>= 1) sum += __shfl_xor(sum, m, 64);
    sh_attn[wid][lane] = e / sum;
    __syncthreads();

    // out: lane = d
    float acc = 0.f;
    for (int k = 0; k < 49; ++k) {
        int lk = l + k - 24;
        if (lk < 0 || lk >= L_) continue;
        acc += sh_attn[wid][k] * kv[((size_t)(n - l + lk)) * 1024 + 512 + h * 64 + lane];
    }
    out[(size_t)n * 512 + h * 64 + lane] = acc;
}

// ---------------------------------------------------------------------------
// In-place RMSNorm over C=512 per row.
// ---------------------------------------------------------------------------
__global__ __launch_bounds__(256) void rmsnorm512(
    float* __restrict__ buf, const float* __restrict__ w)
{
    __shared__ float sws[4];
    const int n = blockIdx.x;
    const int t = threadIdx.x;
    float2 x = *(float2*)(buf + (size_t)n * 512 + t * 2);
    float ss = x.x * x.x + x.y * x.y;
    #pragma unroll
    for (int m = 32; m; m >>= 1) ss += __shfl_xor(ss, m, 64);
    if ((t & 63) == 0) sws[t >> 6] = ss;
    __syncthreads();
    float tot = sws[0] + sws[1] + sws[2] + sws[3];
    float inv = rsqrtf(tot * (1.f / 512.f) + 1e-6f);
    float2 r;
    r.x = x.x * inv * w[t * 2];
    r.y = x.y * inv * w[t * 2 + 1];
    *(float2*)(buf + (size_t)n * 512 + t * 2) = r;
}

// ---------------------------------------------------------------------------
extern "C" void kernel_launch(void* const* d_in, const int* in_sizes, int n_in,
                              void* d_out, int out_size, void* d_ws, size_t ws_size,
                              hipStream_t stream)
{
    const float* x    = (const float*)d_in[0];
    const float* Wq   = (const float*)d_in[1];
    const float* Wkv  = (const float*)d_in[2];
    const float* Wwin = (const float*)d_in[3];
    const float* bwin = (const float*)d_in[4];
    const float* Wg   = (const float*)d_in[5];
    const float* bg   = (const float*)d_in[6];
    const float* Wout = (const float*)d_in[7];
    const float* qn_w = (const float*)d_in[8];
    const float* kn_w = (const float*)d_in[9];
    const float* on_w = (const float*)d_in[10];
    float* outp = (float*)d_out;

    float* q   = (float*)d_ws;                        // NROW*512
    float* kvb = q   + (size_t)NROW * 512;            // NROW*1024
    float* att = kvb + (size_t)NROW * 1024;           // NROW*512
    float* wpb = att + (size_t)NROW * 512;            // NROW*16
    float* merged = q;                                // reuse q after attention

    dim3 blk(256);

    gemm_nt<0><<<dim3(512 / 64, NROW / 64), blk, 0, stream>>>(
        x, 512, Wq, nullptr, q, 512, NROW, 512, 512, nullptr, 0, nullptr, 0);
    gemm_nt<0><<<dim3(1024 / 64, NROW / 64), blk, 0, stream>>>(
        x, 512, Wkv, nullptr, kvb, 1024, NROW, 1024, 512, nullptr, 0, nullptr, 0);
    gemm_nt<0><<<dim3(1, NROW / 64), blk, 0, stream>>>(
        x, 512, Wwin, bwin, wpb, 16, NROW, 16, 512, nullptr, 0, nullptr, 0);

    rms_rope<<<dim3(NUNIT / 4), blk, 0, stream>>>(q, qn_w, 512);
    rms_rope<<<dim3(NUNIT / 4), blk, 0, stream>>>(kvb, kn_w, 1024);

    attn_kernel<<<dim3(NUNIT / 4), blk, 0, stream>>>(q, kvb, wpb, att);

    rmsnorm512<<<dim3(NROW), blk, 0, stream>>>(att, on_w);

    gemm_nt<1><<<dim3(512 / 64, NROW / 64), blk, 0, stream>>>(
        kvb + 512, 1024, Wg, bg, merged, 512, NROW, 512, 512,
        kvb + 512, 1024, att, 512);

    gemm_nt<0><<<dim3(512 / 64, NROW / 64), blk, 0, stream>>>(
        merged, 512, Wout, nullptr, outp, 512, NROW, 512, 512, nullptr, 0, nullptr, 0);
}

// Round 2
// 319.054 us; speedup vs baseline: 2.2047x; 2.2047x over previous
//
#include <hip/hip_runtime.h>
#include <math.h>

#define L_ 4096
#define NROW 8192   // B*L
#define NUNIT 65536 // B*L*H

typedef __attribute__((ext_vector_type(8))) short bf16x8;
typedef __attribute__((ext_vector_type(4))) float f32x4;

__device__ __forceinline__ float sigmoidf_(float x) { return 1.f / (1.f + __expf(-x)); }
__device__ __forceinline__ float siluf_(float x) { return x * sigmoidf_(x); }

__device__ __forceinline__ unsigned short f2bf(float x) {
    union { float f; unsigned int u; } v; v.f = x;
    unsigned int r = v.u + 0x7fff + ((v.u >> 16) & 1);   // RNE
    return (unsigned short)(r >> 16);
}

__device__ __forceinline__ void gll16(const void* g, void* l) {
    auto gp = reinterpret_cast<const __attribute__((address_space(1))) unsigned int*>(
        reinterpret_cast<uintptr_t>(g));
    auto lp = reinterpret_cast<__attribute__((address_space(3))) unsigned int*>(
        reinterpret_cast<uintptr_t>(l));
    __builtin_amdgcn_global_load_lds(gp, lp, 16, 0, 0);
}

// ---------------------------------------------------------------------------
// bf16 MFMA GEMM (NT): C[row,col] = epi( sum_k A[row,k]*W[col,k] )
// A: [M,512] bf16 row-major; W: [N,512] bf16 row-major. K fixed = 512.
// Tile 128x128, 4 waves (2x2), each wave 64x64 via 4x4 frags of 16x16x32.
// EPI 0: silu -> outF (ldo)
// EPI 1: kv: silu -> outF [row*1024+col]; col>=512 also bf16 -> outB[row*512+col-512]
// EPI 2: wp: col<Nstore: silu(acc+bias[col]) -> outF[row*16+col]
// EPI 3: gate-merge: g=sigmoid(silu(acc+bias[col]));
//        outB[row*512+col] = bf16( g*vex[row*1024+col] + (1-g)*oex[row*512+col] )
// ---------------------------------------------------------------------------
template<int EPI>
__global__ __launch_bounds__(256) void mfma_gemm(
    const unsigned short* __restrict__ A,
    const unsigned short* __restrict__ W,
    float* __restrict__ outF,
    unsigned short* __restrict__ outB,
    const float* __restrict__ bias,
    const float* __restrict__ vex,
    const float* __restrict__ oex,
    int ldo, int Nstore)
{
    __shared__ __align__(128) unsigned char lds[16384];
    unsigned char* As = lds;
    unsigned char* Bs = lds + 8192;

    const int tid = threadIdx.x;
    const int w = tid >> 6, lane = tid & 63;
    const int wr = w >> 1, wc = w & 1;
    const int bm = blockIdx.y * 128, bn = blockIdx.x * 128;

    // staging: wave w covers tile rows [w*32, w*32+32), 2 issues of 16 rows
    const unsigned char* gA = (const unsigned char*)A +
        (size_t)(bm + w * 32 + (lane >> 2)) * 1024 + (lane & 3) * 16;
    const unsigned char* gB = (const unsigned char*)W +
        (size_t)(bn + w * 32 + (lane >> 2)) * 1024 + (lane & 3) * 16;
    unsigned char* lA = As + w * 2048;
    unsigned char* lB = Bs + w * 2048;

    f32x4 acc[4][4];
    #pragma unroll
    for (int m = 0; m < 4; ++m)
        #pragma unroll
        for (int n = 0; n < 4; ++n)
            acc[m][n] = (f32x4){0.f, 0.f, 0.f, 0.f};

    const int arow = wr * 64 + (lane & 15);
    const int brow = wc * 64 + (lane & 15);
    const int koff = (lane >> 4) * 16;   // byte offset within 64B row

    for (int k0 = 0; k0 < 512; k0 += 32) {
        gll16(gA + k0 * 2,         lA);
        gll16(gA + k0 * 2 + 16384, lA + 1024);
        gll16(gB + k0 * 2,         lB);
        gll16(gB + k0 * 2 + 16384, lB + 1024);
        __syncthreads();   // drains vmcnt(0) -> LDS tiles ready
        bf16x8 af[4], bfv[4];
        #pragma unroll
        for (int m = 0; m < 4; ++m)
            af[m] = *(const bf16x8*)(As + (arow + m * 16) * 64 + koff);
        #pragma unroll
        for (int n = 0; n < 4; ++n)
            bfv[n] = *(const bf16x8*)(Bs + (brow + n * 16) * 64 + koff);
        #pragma unroll
        for (int m = 0; m < 4; ++m)
            #pragma unroll
            for (int n = 0; n < 4; ++n)
                acc[m][n] = __builtin_amdgcn_mfma_f32_16x16x32_bf16(
                    af[m], bfv[n], acc[m][n], 0, 0, 0);
        __syncthreads();
    }

    const int rb = bm + wr * 64 + (lane >> 4) * 4;
    const int cb = bn + wc * 64 + (lane & 15);
    #pragma unroll
    for (int m = 0; m < 4; ++m) {
        #pragma unroll
        for (int j = 0; j < 4; ++j) {
            const int row = rb + m * 16 + j;
            #pragma unroll
            for (int n = 0; n < 4; ++n) {
                const int col = cb + n * 16;
                float t = acc[m][n][j];
                if (EPI == 0) {
                    outF[(size_t)row * ldo + col] = siluf_(t);
                } else if (EPI == 1) {
                    float r = siluf_(t);
                    outF[(size_t)row * 1024 + col] = r;
                    if (col >= 512) outB[(size_t)row * 512 + (col - 512)] = f2bf(r);
                } else if (EPI == 2) {
                    if (col < Nstore) outF[(size_t)row * 16 + col] = siluf_(t + bias[col]);
                } else if (EPI == 3) {
                    float g = sigmoidf_(siluf_(t + bias[col]));
                    float vv = vex[(size_t)row * 1024 + col];
                    float oo = oex[(size_t)row * 512 + col];
                    outB[(size_t)row * 512 + col] = f2bf(g * vv + (1.f - g) * oo);
                }
            }
        }
    }
}

// ---------------------------------------------------------------------------
__global__ __launch_bounds__(256) void conv_bf16(
    const float* __restrict__ in, unsigned short* __restrict__ out, int n4)
{
    int i = blockIdx.x * 256 + threadIdx.x;
    if (i < n4) {
        float4 v = ((const float4*)in)[i];
        ushort4 o;
        o.x = f2bf(v.x); o.y = f2bf(v.y); o.z = f2bf(v.z); o.w = f2bf(v.w);
        ((ushort4*)out)[i] = o;
    }
}

// Wwin [16,512] -> padded [128,512] bf16, rows >=16 zero
__global__ __launch_bounds__(256) void conv_wwin(
    const float* __restrict__ in, unsigned short* __restrict__ out)
{
    int idx = blockIdx.x * 256 + threadIdx.x;   // 65536 elements
    int r = idx >> 9;
    out[idx] = (r < 16) ? f2bf(in[idx]) : (unsigned short)0;
}

// ---------------------------------------------------------------------------
// Per-(b,l,h) RMSNorm over D=64 + RoPE with pos = h (reference quirk:
// apply_rope uses x.shape[-2]==H as the position axis).
// ---------------------------------------------------------------------------
__global__ __launch_bounds__(256) void rms_rope(
    float* __restrict__ buf, const float* __restrict__ w, int rowStride)
{
    int u = blockIdx.x * 4 + (threadIdx.x >> 6);
    int lane = threadIdx.x & 63;
    int n = u >> 3;
    int h = u & 7;
    size_t off = (size_t)n * rowStride + h * 64 + lane;
    float x = buf[off];
    float ss = x * x;
    #pragma unroll
    for (int m = 32; m; m >>= 1) ss += __shfl_xor(ss, m, 64);
    float inv = rsqrtf(ss * (1.f / 64.f) + 1e-6f);
    float y = x * inv * w[lane];
    float p = __shfl_xor(y, 32, 64);
    int i = lane & 31;
    float freq = powf(10000.f, -(float)i / 32.f);
    float ang = (float)h * freq;
    float s, c;
    sincosf(ang, &s, &c);
    float r = (lane < 32) ? (y * c - p * s) : (p * s + y * c);
    buf[off] = r;
}

// ---------------------------------------------------------------------------
// Windowed attention: one wave per (b,l,h).
// ---------------------------------------------------------------------------
__global__ __launch_bounds__(256) void attn_kernel(
    const float* __restrict__ q4,
    const float* __restrict__ kv,
    const float* __restrict__ wp,
    float* __restrict__ out)
{
    __shared__ float sh_q[4][64];
    __shared__ float sh_attn[4][64];

    const int wid = threadIdx.x >> 6;
    const int lane = threadIdx.x & 63;
    const int u = blockIdx.x * 4 + wid;
    const int n = u >> 3;
    const int h = u & 7;
    const int l = n & (L_ - 1);

    sh_q[wid][lane] = q4[(size_t)n * 512 + h * 64 + lane];

    float wpw = wp[(size_t)n * 16 + h];
    float wps = wp[(size_t)n * 16 + 8 + h];
    float width = 24.f * sigmoidf_(wpw) + 0.5f;
    float sharp = 9.5f * sigmoidf_(wps) + 0.5f;
    __syncthreads();

    float s = -INFINITY;
    if (lane < 49) {
        float rel = fabsf((float)lane - 24.f);
        float mask = sigmoidf_((width - rel) * sharp);
        float dot = 0.f;
        int lk = l + lane - 24;
        if (lk >= 0 && lk < L_) {
            const float4* kp = (const float4*)(kv + ((size_t)(n - l + lk)) * 1024 + h * 64);
            #pragma unroll
            for (int d4 = 0; d4 < 16; ++d4) {
                float4 kq = kp[d4];
                dot += sh_q[wid][d4 * 4 + 0] * kq.x + sh_q[wid][d4 * 4 + 1] * kq.y
                     + sh_q[wid][d4 * 4 + 2] * kq.z + sh_q[wid][d4 * 4 + 3] * kq.w;
            }
        }
        s = dot * 0.125f - (1.f - mask) * 10000.f;
    }
    float mx = s;
    #pragma unroll
    for (int m = 32; m; m >>= 1) mx = fmaxf(mx, __shfl_xor(mx, m, 64));
    float e = __expf(s - mx);
    float sum = e;
    #pragma unroll
    for (int m = 32; m; m >>= 1) sum += __shfl_xor(sum, m, 64);
    sh_attn[wid][lane] = e / sum;
    __syncthreads();

    float acc = 0.f;
    for (int k = 0; k < 49; ++k) {
        int lk = l + k - 24;
        if (lk < 0 || lk >= L_) continue;
        acc += sh_attn[wid][k] * kv[((size_t)(n - l + lk)) * 1024 + 512 + h * 64 + lane];
    }
    out[(size_t)n * 512 + h * 64 + lane] = acc;
}

// ---------------------------------------------------------------------------
__global__ __launch_bounds__(256) void rmsnorm512(
    float* __restrict__ buf, const float* __restrict__ w)
{
    __shared__ float sws[4];
    const int n = blockIdx.x;
    const int t = threadIdx.x;
    float2 x = *(float2*)(buf + (size_t)n * 512 + t * 2);
    float ss = x.x * x.x + x.y * x.y;
    #pragma unroll
    for (int m = 32; m; m >>= 1) ss += __shfl_xor(ss, m, 64);
    if ((t & 63) == 0) sws[t >> 6] = ss;
    __syncthreads();
    float tot = sws[0] + sws[1] + sws[2] + sws[3];
    float inv = rsqrtf(tot * (1.f / 512.f) + 1e-6f);
    float2 r;
    r.x = x.x * inv * w[t * 2];
    r.y = x.y * inv * w[t * 2 + 1];
    *(float2*)(buf + (size_t)n * 512 + t * 2) = r;
}

// ---------------------------------------------------------------------------
extern "C" void kernel_launch(void* const* d_in, const int* in_sizes, int n_in,
                              void* d_out, int out_size, void* d_ws, size_t ws_size,
                              hipStream_t stream)
{
    const float* x    = (const float*)d_in[0];
    const float* Wq   = (const float*)d_in[1];
    const float* Wkv  = (const float*)d_in[2];
    const float* Wwin = (const float*)d_in[3];
    const float* bwin = (const float*)d_in[4];
    const float* Wg   = (const float*)d_in[5];
    const float* bg   = (const float*)d_in[6];
    const float* Wout = (const float*)d_in[7];
    const float* qn_w = (const float*)d_in[8];
    const float* kn_w = (const float*)d_in[9];
    const float* on_w = (const float*)d_in[10];
    float* outp = (float*)d_out;

    // workspace layout
    float* q    = (float*)d_ws;                              // 8192*512 f32
    float* kvb  = q + (size_t)NROW * 512;                    // 8192*1024 f32
    float* wpb  = kvb + (size_t)NROW * 1024;                 // 8192*16 f32
    unsigned short* xbf   = (unsigned short*)(wpb + (size_t)NROW * 16); // 8192*512
    unsigned short* vbf   = xbf + (size_t)NROW * 512;
    unsigned short* wqb   = vbf + (size_t)NROW * 512;        // 512*512
    unsigned short* wkvb  = wqb + 512 * 512;                 // 1024*512
    unsigned short* wgb   = wkvb + 1024 * 512;
    unsigned short* woutb = wgb + 512 * 512;
    unsigned short* wwinb = woutb + 512 * 512;               // 128*512
    unsigned short* mbf   = xbf;                             // reuse xbf after wp gemm
    float* att = outp;                                       // reuse d_out as attention buffer

    dim3 blk(256);

    // conversions
    conv_bf16<<<dim3(NROW * 512 / 4 / 256), blk, 0, stream>>>(x, xbf, NROW * 512 / 4);
    conv_bf16<<<dim3(512 * 512 / 4 / 256), blk, 0, stream>>>(Wq, wqb, 512 * 512 / 4);
    conv_bf16<<<dim3(1024 * 512 / 4 / 256), blk, 0, stream>>>(Wkv, wkvb, 1024 * 512 / 4);
    conv_bf16<<<dim3(512 * 512 / 4 / 256), blk, 0, stream>>>(Wg, wgb, 512 * 512 / 4);
    conv_bf16<<<dim3(512 * 512 / 4 / 256), blk, 0, stream>>>(Wout, woutb, 512 * 512 / 4);
    conv_wwin<<<dim3(128 * 512 / 256), blk, 0, stream>>>(Wwin, wwinb);

    // projections
    mfma_gemm<0><<<dim3(4, 64), blk, 0, stream>>>(
        xbf, wqb, q, nullptr, nullptr, nullptr, nullptr, 512, 512);
    mfma_gemm<1><<<dim3(8, 64), blk, 0, stream>>>(
        xbf, wkvb, kvb, vbf, nullptr, nullptr, nullptr, 1024, 1024);
    mfma_gemm<2><<<dim3(1, 64), blk, 0, stream>>>(
        xbf, wwinb, wpb, nullptr, bwin, nullptr, nullptr, 16, 16);

    // norms + rope (fp32 path)
    rms_rope<<<dim3(NUNIT / 4), blk, 0, stream>>>(q, qn_w, 512);
    rms_rope<<<dim3(NUNIT / 4), blk, 0, stream>>>(kvb, kn_w, 1024);

    attn_kernel<<<dim3(NUNIT / 4), blk, 0, stream>>>(q, kvb, wpb, att);

    rmsnorm512<<<dim3(NROW), blk, 0, stream>>>(att, on_w);

    // gate-merge -> bf16 merged
    mfma_gemm<3><<<dim3(4, 64), blk, 0, stream>>>(
        vbf, wgb, nullptr, mbf, bg, kvb + 512, att, 512, 512);

    // final projection -> d_out
    mfma_gemm<0><<<dim3(4, 64), blk, 0, stream>>>(
        mbf, woutb, outp, nullptr, nullptr, nullptr, nullptr, 512, 512);
}

// Round 4
// 224.449 us; speedup vs baseline: 3.1340x; 1.4215x over previous
//
#include <hip/hip_runtime.h>
#include <math.h>

#define L_ 4096
#define NROW 8192   // B*L
#define KW 112      // window union rows per 64-row tile

typedef __attribute__((ext_vector_type(8))) short bf16x8;
typedef __attribute__((ext_vector_type(4))) float f32x4;

__device__ __forceinline__ float sigmoidf_(float x) { return 1.f / (1.f + __expf(-x)); }
__device__ __forceinline__ float siluf_(float x) { return x * sigmoidf_(x); }

__device__ __forceinline__ unsigned short f2bf(float x) {
    union { float f; unsigned int u; } v; v.f = x;
    unsigned int r = v.u + 0x7fff + ((v.u >> 16) & 1);   // RNE
    return (unsigned short)(r >> 16);
}
__device__ __forceinline__ float bf2f(unsigned short u) {
    union { unsigned int u; float f; } v; v.u = ((unsigned int)u) << 16;
    return v.f;
}

__device__ __forceinline__ void gll16(const void* g, void* l) {
    auto gp = reinterpret_cast<const __attribute__((address_space(1))) unsigned int*>(
        reinterpret_cast<uintptr_t>(g));
    auto lp = reinterpret_cast<__attribute__((address_space(3))) unsigned int*>(
        reinterpret_cast<uintptr_t>(l));
    __builtin_amdgcn_global_load_lds(gp, lp, 16, 0, 0);
}

// ---------------------------------------------------------------------------
// bf16 MFMA GEMM (NT): C[row,col] = epi( sum_k A[row,k]*W[col,k] ), K=512.
// Tile 128x128, 4 waves (2x2), 4x4 frags of 16x16x32.
// EPI 0: silu -> outF f32 [row*ldo+col]            (final projection)
// EPI 1: kv:  silu -> col<512: outB (k) ; col>=512: outB2 (v)  (bf16)
// EPI 2: wp:  col<Nstore: silu(acc+bias) -> outF [row*16+col]
// EPI 3: gate: g=sigmoid(silu(acc+bias)); outB = bf16(g*vex + (1-g)*oex)
// EPI 4: q:   silu -> outB bf16 [row*512+col]
// ---------------------------------------------------------------------------
template<int EPI>
__global__ __launch_bounds__(256) void mfma_gemm(
    const unsigned short* __restrict__ A,
    const unsigned short* __restrict__ W,
    float* __restrict__ outF,
    unsigned short* __restrict__ outB,
    unsigned short* __restrict__ outB2,
    const float* __restrict__ bias,
    const unsigned short* __restrict__ vexB,
    const float* __restrict__ oexF,
    int ldo, int Nstore)
{
    __shared__ __align__(128) unsigned char lds[16384];
    unsigned char* As = lds;
    unsigned char* Bs = lds + 8192;

    const int tid = threadIdx.x;
    const int w = tid >> 6, lane = tid & 63;
    const int wr = w >> 1, wc = w & 1;
    const int bm = blockIdx.y * 128, bn = blockIdx.x * 128;

    const unsigned char* gA = (const unsigned char*)A +
        (size_t)(bm + w * 32 + (lane >> 2)) * 1024 + (lane & 3) * 16;
    const unsigned char* gB = (const unsigned char*)W +
        (size_t)(bn + w * 32 + (lane >> 2)) * 1024 + (lane & 3) * 16;
    unsigned char* lA = As + w * 2048;
    unsigned char* lB = Bs + w * 2048;

    f32x4 acc[4][4];
    #pragma unroll
    for (int m = 0; m < 4; ++m)
        #pragma unroll
        for (int n = 0; n < 4; ++n)
            acc[m][n] = (f32x4){0.f, 0.f, 0.f, 0.f};

    const int arow = wr * 64 + (lane & 15);
    const int brow = wc * 64 + (lane & 15);
    const int koff = (lane >> 4) * 16;

    for (int k0 = 0; k0 < 512; k0 += 32) {
        gll16(gA + k0 * 2,         lA);
        gll16(gA + k0 * 2 + 16384, lA + 1024);
        gll16(gB + k0 * 2,         lB);
        gll16(gB + k0 * 2 + 16384, lB + 1024);
        __syncthreads();
        bf16x8 af[4], bfv[4];
        #pragma unroll
        for (int m = 0; m < 4; ++m)
            af[m] = *(const bf16x8*)(As + (arow + m * 16) * 64 + koff);
        #pragma unroll
        for (int n = 0; n < 4; ++n)
            bfv[n] = *(const bf16x8*)(Bs + (brow + n * 16) * 64 + koff);
        #pragma unroll
        for (int m = 0; m < 4; ++m)
            #pragma unroll
            for (int n = 0; n < 4; ++n)
                acc[m][n] = __builtin_amdgcn_mfma_f32_16x16x32_bf16(
                    af[m], bfv[n], acc[m][n], 0, 0, 0);
        __syncthreads();
    }

    const int rb = bm + wr * 64 + (lane >> 4) * 4;
    const int cb = bn + wc * 64 + (lane & 15);
    #pragma unroll
    for (int m = 0; m < 4; ++m) {
        #pragma unroll
        for (int j = 0; j < 4; ++j) {
            const int row = rb + m * 16 + j;
            #pragma unroll
            for (int n = 0; n < 4; ++n) {
                const int col = cb + n * 16;
                float t = acc[m][n][j];
                if (EPI == 0) {
                    outF[(size_t)row * ldo + col] = siluf_(t);
                } else if (EPI == 1) {
                    float r = siluf_(t);
                    if (col < 512) outB[(size_t)row * 512 + col] = f2bf(r);
                    else           outB2[(size_t)row * 512 + (col - 512)] = f2bf(r);
                } else if (EPI == 2) {
                    if (col < Nstore) outF[(size_t)row * 16 + col] = siluf_(t + bias[col]);
                } else if (EPI == 3) {
                    float g = sigmoidf_(siluf_(t + bias[col]));
                    float vv = bf2f(vexB[(size_t)row * 512 + col]);
                    float oo = oexF[(size_t)row * 512 + col];
                    outB[(size_t)row * 512 + col] = f2bf(g * vv + (1.f - g) * oo);
                } else if (EPI == 4) {
                    outB[(size_t)row * 512 + col] = f2bf(siluf_(t));
                }
            }
        }
    }
}

// ---------------------------------------------------------------------------
__global__ __launch_bounds__(256) void conv_bf16(
    const float* __restrict__ in, unsigned short* __restrict__ out, int n4)
{
    int i = blockIdx.x * 256 + threadIdx.x;
    if (i < n4) {
        float4 v = ((const float4*)in)[i];
        ushort4 o;
        o.x = f2bf(v.x); o.y = f2bf(v.y); o.z = f2bf(v.z); o.w = f2bf(v.w);
        ((ushort4*)out)[i] = o;
    }
}

__global__ __launch_bounds__(256) void conv_wwin(
    const float* __restrict__ in, unsigned short* __restrict__ out)
{
    int idx = blockIdx.x * 256 + threadIdx.x;   // 65536
    int r = idx >> 9;
    out[idx] = (r < 16) ? f2bf(in[idx]) : (unsigned short)0;
}

// ---------------------------------------------------------------------------
// Fused windowed attention, MFMA. One block per (b, h, 64-row l-tile).
// Stages Q (rmsnorm+rope fused), K (rmsnorm+rope, zero-pad OOB), Vt (transposed)
// as bf16 in LDS. S^T = K*Q^T per wave-strip (16 l-rows), in-register softmax,
// P -> LDS, O = P*V. RoPE pos = h (reference quirk: x.shape[-2]==H).
// ---------------------------------------------------------------------------
__global__ __launch_bounds__(256) void attn_fused(
    const unsigned short* __restrict__ qb,
    const unsigned short* __restrict__ kb,
    const unsigned short* __restrict__ vb,
    const float* __restrict__ wpb,
    const float* __restrict__ qn_w,
    const float* __restrict__ kn_w,
    float* __restrict__ att)
{
    __shared__ __align__(16) unsigned short Q_lds[64][72];
    __shared__ __align__(16) unsigned short K_lds[112][72];
    __shared__ __align__(16) unsigned short Vt[64][136];
    __shared__ __align__(16) unsigned short P_A[64][136];
    __shared__ float widths[64], sharps[64];

    const int tid = threadIdx.x, wid = tid >> 6, lane = tid & 63;
    const int bid = blockIdx.x;
    const int tile = bid & 63, h = (bid >> 6) & 7, b = bid >> 9;
    const int l0 = tile * 64;
    const int n0 = b * L_ + l0;

    // zero the w-padding (112..127) of Vt and P_A
    {
        int r = tid >> 2, c4 = 112 + (tid & 3) * 4;
        *(uint2*)&Vt[r][c4]  = make_uint2(0u, 0u);
        *(uint2*)&P_A[r][c4] = make_uint2(0u, 0u);
    }
    // wp params
    if (tid < 64) {
        float w_ = wpb[(size_t)(n0 + tid) * 16 + h];
        float s_ = wpb[(size_t)(n0 + tid) * 16 + 8 + h];
        widths[tid] = 24.f * sigmoidf_(w_) + 0.5f;
        sharps[tid] = 9.5f * sigmoidf_(s_) + 0.5f;
    }

    // per-lane rope constants (pos = h, freq by d&31); lanes hold d = dl, dl+1
    const int half = lane >> 5;
    const int dl = (lane & 31) * 2;
    const int i0 = dl & 31;
    const float lg = -13.287712379549449f / 32.f;  // -log2(10000)/32
    float fr0 = exp2f((float)i0 * lg);
    float fr1 = exp2f((float)(i0 + 1) * lg);
    float s0, c0, s1, c1;
    sincosf((float)h * fr0, &s0, &c0);
    sincosf((float)h * fr1, &s1, &c1);
    const bool lohalf = (lane & 16) == 0;
    const float qw0 = qn_w[dl], qw1 = qn_w[dl + 1];
    const float kw0 = kn_w[dl], kw1 = kn_w[dl + 1];

    // ---- Q staging: wave handles rows [wid*16, wid*16+16), 2 rows/iter
    #pragma unroll
    for (int it = 0; it < 8; ++it) {
        int r = wid * 16 + it * 2 + half;
        unsigned int pk = *(const unsigned int*)(qb + (size_t)(n0 + r) * 512 + h * 64 + dl);
        float x0 = bf2f((unsigned short)(pk & 0xffff));
        float x1 = bf2f((unsigned short)(pk >> 16));
        float ss = x0 * x0 + x1 * x1;
        #pragma unroll
        for (int m = 16; m; m >>= 1) ss += __shfl_xor(ss, m, 64);
        float inv = rsqrtf(ss * (1.f / 64.f) + 1e-6f);
        float y0 = x0 * inv * qw0, y1 = x1 * inv * qw1;
        float p0 = __shfl_xor(y0, 16, 64), p1 = __shfl_xor(y1, 16, 64);
        float o0 = lohalf ? (y0 * c0 - p0 * s0) : (p0 * s0 + y0 * c0);
        float o1 = lohalf ? (y1 * c1 - p1 * s1) : (p1 * s1 + y1 * c1);
        *(unsigned int*)&Q_lds[r][dl] =
            (unsigned int)f2bf(o0) | ((unsigned int)f2bf(o1) << 16);
    }

    // ---- K staging: wave handles rows [wid*28, wid*28+28), 2 rows/iter
    #pragma unroll
    for (int it = 0; it < 14; ++it) {
        int wrow = wid * 28 + it * 2 + half;
        int abs_l = l0 - 24 + wrow;
        unsigned int res = 0;
        if (abs_l >= 0 && abs_l < L_) {
            unsigned int pk = *(const unsigned int*)(kb + (size_t)(b * L_ + abs_l) * 512 + h * 64 + dl);
            float x0 = bf2f((unsigned short)(pk & 0xffff));
            float x1 = bf2f((unsigned short)(pk >> 16));
            float ss = x0 * x0 + x1 * x1;
            #pragma unroll
            for (int m = 16; m; m >>= 1) ss += __shfl_xor(ss, m, 64);
            float inv = rsqrtf(ss * (1.f / 64.f) + 1e-6f);
            float y0 = x0 * inv * kw0, y1 = x1 * inv * kw1;
            float p0 = __shfl_xor(y0, 16, 64), p1 = __shfl_xor(y1, 16, 64);
            float o0 = lohalf ? (y0 * c0 - p0 * s0) : (p0 * s0 + y0 * c0);
            float o1 = lohalf ? (y1 * c1 - p1 * s1) : (p1 * s1 + y1 * c1);
            res = (unsigned int)f2bf(o0) | ((unsigned int)f2bf(o1) << 16);
        }
        *(unsigned int*)&K_lds[wrow][dl] = res;
    }

    // ---- V staging (transposed): wave handles w in [wid*28, wid*28+28)
    #pragma unroll
    for (int it = 0; it < 28; ++it) {
        int wrow = wid * 28 + it;
        int abs_l = l0 - 24 + wrow;
        unsigned short val = 0;
        if (abs_l >= 0 && abs_l < L_)
            val = vb[(size_t)(b * L_ + abs_l) * 512 + h * 64 + lane];
        Vt[lane][wrow] = val;
    }

    __syncthreads();

    // ---- QK^T: S^T[w][l] for this wave's l-strip (l = wid*16 + lane&15)
    const int fr = lane & 15, fq = lane >> 4;
    f32x4 sacc[7];
    #pragma unroll
    for (int mf = 0; mf < 7; ++mf) sacc[mf] = (f32x4){0.f, 0.f, 0.f, 0.f};

    bf16x8 bq[2];
    #pragma unroll
    for (int ks = 0; ks < 2; ++ks)
        bq[ks] = *(const bf16x8*)&Q_lds[wid * 16 + fr][ks * 32 + fq * 8];
    #pragma unroll
    for (int mf = 0; mf < 7; ++mf) {
        #pragma unroll
        for (int ks = 0; ks < 2; ++ks) {
            bf16x8 ak = *(const bf16x8*)&K_lds[mf * 16 + fr][ks * 32 + fq * 8];
            sacc[mf] = __builtin_amdgcn_mfma_f32_16x16x32_bf16(ak, bq[ks], sacc[mf], 0, 0, 0);
        }
    }

    // ---- softmax: lane's row l = wid*16 + fr; its w values: mf*16 + fq*4 + jj
    const int rl = wid * 16 + fr;
    const float wd = widths[rl], sh = sharps[rl];
    float vals[28];
    float mx = -1e30f;
    #pragma unroll
    for (int mf = 0; mf < 7; ++mf) {
        #pragma unroll
        for (int jj = 0; jj < 4; ++jj) {
            int wv = mf * 16 + fq * 4 + jj;
            int kk = wv - rl;
            float sc = -1e30f;
            if (kk >= 0 && kk <= 48) {
                float rel = fabsf((float)kk - 24.f);
                float msk = sigmoidf_((wd - rel) * sh);
                sc = sacc[mf][jj] * 0.125f - (1.f - msk) * 10000.f;
            }
            vals[mf * 4 + jj] = sc;
            mx = fmaxf(mx, sc);
        }
    }
    mx = fmaxf(mx, __shfl_xor(mx, 16, 64));
    mx = fmaxf(mx, __shfl_xor(mx, 32, 64));
    float sum = 0.f;
    #pragma unroll
    for (int i = 0; i < 28; ++i) {
        float e = __expf(vals[i] - mx);
        vals[i] = e;
        sum += e;
    }
    sum += __shfl_xor(sum, 16, 64);
    sum += __shfl_xor(sum, 32, 64);
    float rs = 1.f / sum;

    // write P (row-major [l][w]) — 4 consecutive w per mf -> b64 writes
    #pragma unroll
    for (int mf = 0; mf < 7; ++mf) {
        unsigned int lo_ = (unsigned int)f2bf(vals[mf * 4 + 0] * rs)
                         | ((unsigned int)f2bf(vals[mf * 4 + 1] * rs) << 16);
        unsigned int hi_ = (unsigned int)f2bf(vals[mf * 4 + 2] * rs)
                         | ((unsigned int)f2bf(vals[mf * 4 + 3] * rs) << 16);
        *(uint2*)&P_A[rl][mf * 16 + fq * 4] = make_uint2(lo_, hi_);
    }

    // ---- PV: O[l][d] for this wave's strip; A=P rows, B=Vt rows (d)
    f32x4 oacc[4];
    #pragma unroll
    for (int nf = 0; nf < 4; ++nf) oacc[nf] = (f32x4){0.f, 0.f, 0.f, 0.f};
    #pragma unroll
    for (int ks = 0; ks < 4; ++ks) {
        bf16x8 ap = *(const bf16x8*)&P_A[wid * 16 + fr][ks * 32 + fq * 8];
        #pragma unroll
        for (int nf = 0; nf < 4; ++nf) {
            bf16x8 bv = *(const bf16x8*)&Vt[nf * 16 + fr][ks * 32 + fq * 8];
            oacc[nf] = __builtin_amdgcn_mfma_f32_16x16x32_bf16(ap, bv, oacc[nf], 0, 0, 0);
        }
    }

    // ---- store O (f32) to att
    const int orow = n0 + wid * 16 + fq * 4;
    #pragma unroll
    for (int nf = 0; nf < 4; ++nf)
        #pragma unroll
        for (int jj = 0; jj < 4; ++jj)
            att[(size_t)(orow + jj) * 512 + h * 64 + nf * 16 + fr] = oacc[nf][jj];
}

// ---------------------------------------------------------------------------
__global__ __launch_bounds__(256) void rmsnorm512(
    float* __restrict__ buf, const float* __restrict__ w)
{
    __shared__ float sws[4];
    const int n = blockIdx.x;
    const int t = threadIdx.x;
    float2 x = *(float2*)(buf + (size_t)n * 512 + t * 2);
    float ss = x.x * x.x + x.y * x.y;
    #pragma unroll
    for (int m = 32; m; m >>= 1) ss += __shfl_xor(ss, m, 64);
    if ((t & 63) == 0) sws[t >> 6] = ss;
    __syncthreads();
    float tot = sws[0] + sws[1] + sws[2] + sws[3];
    float inv = rsqrtf(tot * (1.f / 512.f) + 1e-6f);
    float2 r;
    r.x = x.x * inv * w[t * 2];
    r.y = x.y * inv * w[t * 2 + 1];
    *(float2*)(buf + (size_t)n * 512 + t * 2) = r;
}

// ---------------------------------------------------------------------------
extern "C" void kernel_launch(void* const* d_in, const int* in_sizes, int n_in,
                              void* d_out, int out_size, void* d_ws, size_t ws_size,
                              hipStream_t stream)
{
    const float* x    = (const float*)d_in[0];
    const float* Wq   = (const float*)d_in[1];
    const float* Wkv  = (const float*)d_in[2];
    const float* Wwin = (const float*)d_in[3];
    const float* bwin = (const float*)d_in[4];
    const float* Wg   = (const float*)d_in[5];
    const float* bg   = (const float*)d_in[6];
    const float* Wout = (const float*)d_in[7];
    const float* qn_w = (const float*)d_in[8];
    const float* kn_w = (const float*)d_in[9];
    const float* on_w = (const float*)d_in[10];
    float* outp = (float*)d_out;

    // workspace layout (bf16 buffers unless noted)
    unsigned short* xbf  = (unsigned short*)d_ws;            // 8192*512
    unsigned short* qbB  = xbf  + (size_t)NROW * 512;
    unsigned short* kbB  = qbB  + (size_t)NROW * 512;
    unsigned short* vbB  = kbB  + (size_t)NROW * 512;
    unsigned short* wqb  = vbB  + (size_t)NROW * 512;        // 512*512
    unsigned short* wkvb = wqb  + 512 * 512;                 // 1024*512
    unsigned short* wgb  = wkvb + 1024 * 512;
    unsigned short* woutb= wgb  + 512 * 512;
    unsigned short* wwinb= woutb+ 512 * 512;                 // 128*512
    float* wpb = (float*)(wwinb + 128 * 512);                // 8192*16 f32
    unsigned short* mbf = xbf;                               // reuse xbf after gate
    float* att = outp;                                       // reuse d_out

    dim3 blk(256);

    conv_bf16<<<dim3(NROW * 512 / 4 / 256), blk, 0, stream>>>(x, xbf, NROW * 512 / 4);
    conv_bf16<<<dim3(512 * 512 / 4 / 256), blk, 0, stream>>>(Wq, wqb, 512 * 512 / 4);
    conv_bf16<<<dim3(1024 * 512 / 4 / 256), blk, 0, stream>>>(Wkv, wkvb, 1024 * 512 / 4);
    conv_bf16<<<dim3(512 * 512 / 4 / 256), blk, 0, stream>>>(Wg, wgb, 512 * 512 / 4);
    conv_bf16<<<dim3(512 * 512 / 4 / 256), blk, 0, stream>>>(Wout, woutb, 512 * 512 / 4);
    conv_wwin<<<dim3(128 * 512 / 256), blk, 0, stream>>>(Wwin, wwinb);

    // projections (bf16 outputs for q/k/v; f32 for wp)
    mfma_gemm<4><<<dim3(4, 64), blk, 0, stream>>>(
        xbf, wqb, nullptr, qbB, nullptr, nullptr, nullptr, nullptr, 512, 512);
    mfma_gemm<1><<<dim3(8, 64), blk, 0, stream>>>(
        xbf, wkvb, nullptr, kbB, vbB, nullptr, nullptr, nullptr, 1024, 1024);
    mfma_gemm<2><<<dim3(1, 64), blk, 0, stream>>>(
        xbf, wwinb, wpb, nullptr, nullptr, bwin, nullptr, nullptr, 16, 16);

    // fused attention (rmsnorm+rope inside)
    attn_fused<<<dim3(1024), blk, 0, stream>>>(qbB, kbB, vbB, wpb, qn_w, kn_w, att);

    rmsnorm512<<<dim3(NROW), blk, 0, stream>>>(att, on_w);

    // gate-merge -> bf16 merged
    mfma_gemm<3><<<dim3(4, 64), blk, 0, stream>>>(
        vbB, wgb, nullptr, mbf, nullptr, bg, vbB, att, 512, 512);

    // final projection -> d_out (f32)
    mfma_gemm<0><<<dim3(4, 64), blk, 0, stream>>>(
        mbf, woutb, outp, nullptr, nullptr, nullptr, nullptr, nullptr, 512, 512);
}

// Round 5
// 176.995 us; speedup vs baseline: 3.9742x; 1.2681x over previous
//
#include <hip/hip_runtime.h>
#include <math.h>

#define L_ 4096
#define NROW 8192   // B*L

typedef __attribute__((ext_vector_type(8))) short bf16x8;
typedef __attribute__((ext_vector_type(4))) float f32x4;

__device__ __forceinline__ float sigmoidf_(float x) { return 1.f / (1.f + __expf(-x)); }
__device__ __forceinline__ float siluf_(float x) { return x * sigmoidf_(x); }

__device__ __forceinline__ unsigned short f2bf(float x) {
    union { float f; unsigned int u; } v; v.f = x;
    unsigned int r = v.u + 0x7fff + ((v.u >> 16) & 1);   // RNE
    return (unsigned short)(r >> 16);
}
__device__ __forceinline__ float bf2f(unsigned short u) {
    union { unsigned int u; float f; } v; v.u = ((unsigned int)u) << 16;
    return v.f;
}

__device__ __forceinline__ void gll16(const void* g, void* l) {
    auto gp = reinterpret_cast<const __attribute__((address_space(1))) unsigned int*>(
        reinterpret_cast<uintptr_t>(g));
    auto lp = reinterpret_cast<__attribute__((address_space(3))) unsigned int*>(
        reinterpret_cast<uintptr_t>(l));
    __builtin_amdgcn_global_load_lds(gp, lp, 16, 0, 0);
}

// ---------------------------------------------------------------------------
// bf16 MFMA GEMM (NT), K = 512, BN = 128, BM in {128, 64}, 4 waves (2x2).
// EPI 0:  out-proj: silu -> outF f32 [row*512+col]
// EPI 3:  gate: g=sigmoid(silu(acc+bias[col])); vv=bf2f(A[row,col]);
//         oo=extraF0[row*512+col]*extraF1[row]*extraF2[col];
//         outB0 = bf16(g*vv + (1-g)*oo)
// EPI 10: fused qkv+wp: bn<512 -> q bf16 (outB0); bn<1536 -> k/v bf16
//         (outB1/outB2); else wp: silu(acc+bias)->outF [row*16+lc], lc<16
// ---------------------------------------------------------------------------
template<int EPI, int BM>
__global__ __launch_bounds__(256) void mfma_gemm(
    const unsigned short* __restrict__ A,
    const unsigned short* __restrict__ W0,
    const unsigned short* __restrict__ W1,
    const unsigned short* __restrict__ W2,
    float* __restrict__ outF,
    unsigned short* __restrict__ outB0,
    unsigned short* __restrict__ outB1,
    unsigned short* __restrict__ outB2,
    const float* __restrict__ bias,
    const float* __restrict__ extraF0,
    const float* __restrict__ extraF1,
    const float* __restrict__ extraF2)
{
    constexpr int MF = BM / 32;          // m-frags per wave (4 or 2)
    constexpr int ARW = BM / 4;          // A rows per wave (32 or 16)
    __shared__ __align__(128) unsigned char lds[BM * 64 + 8192];
    unsigned char* As = lds;
    unsigned char* Bs = lds + BM * 64;

    const int tid = threadIdx.x;
    const int w = tid >> 6, lane = tid & 63;
    const int wr = w >> 1, wc = w & 1;
    const int bm = blockIdx.y * BM, bn = blockIdx.x * 128;

    // B source selection (uniform per block)
    const unsigned short* Wsel;
    int bnl;
    if (EPI == 10) {
        if (bn < 512)       { Wsel = W0; bnl = bn; }
        else if (bn < 1536) { Wsel = W1; bnl = bn - 512; }
        else                { Wsel = W2; bnl = bn - 1536; }
    } else { Wsel = W0; bnl = bn; }

    const unsigned char* gA = (const unsigned char*)A +
        (size_t)(bm + w * ARW + (lane >> 2)) * 1024 + (lane & 3) * 16;
    const unsigned char* gB = (const unsigned char*)Wsel +
        (size_t)(bnl + w * 32 + (lane >> 2)) * 1024 + (lane & 3) * 16;
    unsigned char* lA = As + w * ARW * 64;
    unsigned char* lB = Bs + w * 2048;

    f32x4 acc[MF][4];
    #pragma unroll
    for (int m = 0; m < MF; ++m)
        #pragma unroll
        for (int n = 0; n < 4; ++n)
            acc[m][n] = (f32x4){0.f, 0.f, 0.f, 0.f};

    const int arow = wr * (BM / 2) + (lane & 15);
    const int brow = wc * 64 + (lane & 15);
    const int koff = (lane >> 4) * 16;

    for (int k0 = 0; k0 < 512; k0 += 32) {
        gll16(gA + k0 * 2, lA);
        if (BM == 128) gll16(gA + k0 * 2 + 16384, lA + 1024);
        gll16(gB + k0 * 2,         lB);
        gll16(gB + k0 * 2 + 16384, lB + 1024);
        __syncthreads();
        bf16x8 af[MF], bfv[4];
        #pragma unroll
        for (int m = 0; m < MF; ++m)
            af[m] = *(const bf16x8*)(As + (arow + m * 16) * 64 + koff);
        #pragma unroll
        for (int n = 0; n < 4; ++n)
            bfv[n] = *(const bf16x8*)(Bs + (brow + n * 16) * 64 + koff);
        #pragma unroll
        for (int m = 0; m < MF; ++m)
            #pragma unroll
            for (int n = 0; n < 4; ++n)
                acc[m][n] = __builtin_amdgcn_mfma_f32_16x16x32_bf16(
                    af[m], bfv[n], acc[m][n], 0, 0, 0);
        __syncthreads();
    }

    const int rb = bm + wr * (BM / 2) + (lane >> 4) * 4;
    const int cb = bn + wc * 64 + (lane & 15);
    #pragma unroll
    for (int m = 0; m < MF; ++m) {
        #pragma unroll
        for (int j = 0; j < 4; ++j) {
            const int row = rb + m * 16 + j;
            #pragma unroll
            for (int n = 0; n < 4; ++n) {
                const int col = cb + n * 16;
                float t = acc[m][n][j];
                if (EPI == 0) {
                    outF[(size_t)row * 512 + col] = siluf_(t);
                } else if (EPI == 3) {
                    float g = sigmoidf_(siluf_(t + bias[col]));
                    float vv = bf2f(A[(size_t)row * 512 + col]);
                    float oo = extraF0[(size_t)row * 512 + col] * extraF1[row] * extraF2[col];
                    outB0[(size_t)row * 512 + col] = f2bf(g * vv + (1.f - g) * oo);
                } else if (EPI == 10) {
                    float r = siluf_(t);
                    if (bn < 512) {
                        outB0[(size_t)row * 512 + col] = f2bf(r);
                    } else if (bn < 1536) {
                        int lc = col - 512;
                        if (lc < 512) outB1[(size_t)row * 512 + lc] = f2bf(r);
                        else          outB2[(size_t)row * 512 + (lc - 512)] = f2bf(r);
                    } else {
                        int lc = col - 1536;
                        if (lc < 16) outF[(size_t)row * 16 + lc] = siluf_(t + bias[lc]);
                    }
                }
            }
        }
    }
}

// ---------------------------------------------------------------------------
__global__ __launch_bounds__(256) void conv_bf16(
    const float* __restrict__ in, unsigned short* __restrict__ out, int n4)
{
    int i = blockIdx.x * 256 + threadIdx.x;
    if (i < n4) {
        float4 v = ((const float4*)in)[i];
        ushort4 o;
        o.x = f2bf(v.x); o.y = f2bf(v.y); o.z = f2bf(v.z); o.w = f2bf(v.w);
        ((ushort4*)out)[i] = o;
    }
}

// all four big weights in one dispatch: y selects a 65536-float4 segment
__global__ __launch_bounds__(256) void conv_w5(
    const float* __restrict__ Wq, const float* __restrict__ Wkv,
    const float* __restrict__ Wg, const float* __restrict__ Wout,
    unsigned short* __restrict__ wqb, unsigned short* __restrict__ wkvb,
    unsigned short* __restrict__ wgb, unsigned short* __restrict__ woutb)
{
    int y = blockIdx.y;
    int i = blockIdx.x * 256 + threadIdx.x;
    const float* src;
    unsigned short* dst;
    if (y == 0)      { src = Wq;            dst = wqb; }
    else if (y == 1) { src = Wkv;           dst = wkvb; }
    else if (y == 2) { src = Wkv + 262144;  dst = wkvb + 262144; }
    else if (y == 3) { src = Wg;            dst = wgb; }
    else             { src = Wout;          dst = woutb; }
    float4 v = ((const float4*)src)[i];
    ushort4 o;
    o.x = f2bf(v.x); o.y = f2bf(v.y); o.z = f2bf(v.z); o.w = f2bf(v.w);
    ((ushort4*)dst)[i] = o;
}

__global__ __launch_bounds__(256) void conv_wwin(
    const float* __restrict__ in, unsigned short* __restrict__ out)
{
    int idx = blockIdx.x * 256 + threadIdx.x;   // 65536
    int r = idx >> 9;
    out[idx] = (r < 16) ? f2bf(in[idx]) : (unsigned short)0;
}

// ---------------------------------------------------------------------------
// Fused windowed attention. One block per (b, h, 64-row l-tile), 4 waves.
// LDS aliasing: P overlays Q+K (dead after QK^T, guarded by a barrier).
// RoPE pos = h (reference quirk: x.shape[-2]==H).
// ---------------------------------------------------------------------------
__global__ __launch_bounds__(256) void attn_fused(
    const unsigned short* __restrict__ qb,
    const unsigned short* __restrict__ kb,
    const unsigned short* __restrict__ vb,
    const float* __restrict__ wpb,
    const float* __restrict__ qn_w,
    const float* __restrict__ kn_w,
    float* __restrict__ att)
{
    __shared__ __align__(16) unsigned char smem[43264];
    auto Q_lds  = (unsigned short(*)[72])(smem);            // 9216 B
    auto K_lds  = (unsigned short(*)[72])(smem + 9216);     // 16128 B
    auto P_A    = (unsigned short(*)[136])(smem);           // 17408 B, aliases Q+K
    auto Vt     = (unsigned short(*)[136])(smem + 25344);   // 17408 B
    float* widths = (float*)(smem + 42752);
    float* sharps = (float*)(smem + 43008);

    const int tid = threadIdx.x, wid = tid >> 6, lane = tid & 63;
    const int bid = blockIdx.x;
    const int tile = bid & 63, h = (bid >> 6) & 7, b = bid >> 9;
    const int l0 = tile * 64;
    const int n0 = b * L_ + l0;

    // Vt zero-pad (cols 112..127); rows tid>>2 covers 0..63
    {
        int r = tid >> 2, c4 = 112 + (tid & 3) * 4;
        *(uint2*)&Vt[r][c4] = make_uint2(0u, 0u);
    }
    if (tid < 64) {
        float w_ = wpb[(size_t)(n0 + tid) * 16 + h];
        float s_ = wpb[(size_t)(n0 + tid) * 16 + 8 + h];
        widths[tid] = 24.f * sigmoidf_(w_) + 0.5f;
        sharps[tid] = 9.5f * sigmoidf_(s_) + 0.5f;
    }

    // per-lane rope constants (pos = h); lanes hold d = dl, dl+1
    const int half = lane >> 5;
    const int dl = (lane & 31) * 2;
    const float lg = -13.287712379549449f / 32.f;  // -log2(10000)/32... (ln, via exp2f)
    float fr0 = exp2f((float)(dl & 31) * lg);
    float fr1 = exp2f((float)((dl & 31) + 1) * lg);
    float s0, c0, s1, c1;
    sincosf((float)h * fr0, &s0, &c0);
    sincosf((float)h * fr1, &s1, &c1);
    const bool lohalf = (lane & 16) == 0;
    const float qw0 = qn_w[dl], qw1 = qn_w[dl + 1];
    const float kw0 = kn_w[dl], kw1 = kn_w[dl + 1];

    // ---- Q staging: wave rows [wid*16, wid*16+16), 2 rows/iter
    #pragma unroll
    for (int it = 0; it < 8; ++it) {
        int r = wid * 16 + it * 2 + half;
        unsigned int pk = *(const unsigned int*)(qb + (size_t)(n0 + r) * 512 + h * 64 + dl);
        float x0 = bf2f((unsigned short)(pk & 0xffff));
        float x1 = bf2f((unsigned short)(pk >> 16));
        float ss = x0 * x0 + x1 * x1;
        #pragma unroll
        for (int m = 16; m; m >>= 1) ss += __shfl_xor(ss, m, 64);
        float inv = rsqrtf(ss * (1.f / 64.f) + 1e-6f);
        float y0 = x0 * inv * qw0, y1 = x1 * inv * qw1;
        float p0 = __shfl_xor(y0, 16, 64), p1 = __shfl_xor(y1, 16, 64);
        float o0 = lohalf ? (y0 * c0 - p0 * s0) : (p0 * s0 + y0 * c0);
        float o1 = lohalf ? (y1 * c1 - p1 * s1) : (p1 * s1 + y1 * c1);
        *(unsigned int*)&Q_lds[r][dl] =
            (unsigned int)f2bf(o0) | ((unsigned int)f2bf(o1) << 16);
    }

    // ---- K staging: wave rows [wid*28, wid*28+28), 2 rows/iter
    #pragma unroll
    for (int it = 0; it < 14; ++it) {
        int wrow = wid * 28 + it * 2 + half;
        int abs_l = l0 - 24 + wrow;
        unsigned int res = 0;
        if (abs_l >= 0 && abs_l < L_) {
            unsigned int pk = *(const unsigned int*)(kb + (size_t)(b * L_ + abs_l) * 512 + h * 64 + dl);
            float x0 = bf2f((unsigned short)(pk & 0xffff));
            float x1 = bf2f((unsigned short)(pk >> 16));
            float ss = x0 * x0 + x1 * x1;
            #pragma unroll
            for (int m = 16; m; m >>= 1) ss += __shfl_xor(ss, m, 64);
            float inv = rsqrtf(ss * (1.f / 64.f) + 1e-6f);
            float y0 = x0 * inv * kw0, y1 = x1 * inv * kw1;
            float p0 = __shfl_xor(y0, 16, 64), p1 = __shfl_xor(y1, 16, 64);
            float o0 = lohalf ? (y0 * c0 - p0 * s0) : (p0 * s0 + y0 * c0);
            float o1 = lohalf ? (y1 * c1 - p1 * s1) : (p1 * s1 + y1 * c1);
            res = (unsigned int)f2bf(o0) | ((unsigned int)f2bf(o1) << 16);
        }
        *(unsigned int*)&K_lds[wrow][dl] = res;
    }

    // ---- V staging (transposed): wave cols w in [wid*28, wid*28+28)
    #pragma unroll
    for (int it = 0; it < 28; ++it) {
        int wrow = wid * 28 + it;
        int abs_l = l0 - 24 + wrow;
        unsigned short val = 0;
        if (abs_l >= 0 && abs_l < L_)
            val = vb[(size_t)(b * L_ + abs_l) * 512 + h * 64 + lane];
        Vt[lane][wrow] = val;
    }

    __syncthreads();

    // ---- QK^T: S^T[w][l] for this wave's l-strip
    const int fr = lane & 15, fq = lane >> 4;
    f32x4 sacc[7];
    #pragma unroll
    for (int mf = 0; mf < 7; ++mf) sacc[mf] = (f32x4){0.f, 0.f, 0.f, 0.f};

    bf16x8 bq[2];
    #pragma unroll
    for (int ks = 0; ks < 2; ++ks)
        bq[ks] = *(const bf16x8*)&Q_lds[wid * 16 + fr][ks * 32 + fq * 8];
    #pragma unroll
    for (int mf = 0; mf < 7; ++mf) {
        #pragma unroll
        for (int ks = 0; ks < 2; ++ks) {
            bf16x8 ak = *(const bf16x8*)&K_lds[mf * 16 + fr][ks * 32 + fq * 8];
            sacc[mf] = __builtin_amdgcn_mfma_f32_16x16x32_bf16(ak, bq[ks], sacc[mf], 0, 0, 0);
        }
    }

    __syncthreads();   // Q/K reads complete in ALL waves -> P may overlay them

    // P zero-pad (cols 112..127): wave w's threads cover w's own rows
    {
        int r = tid >> 2, c4 = 112 + (tid & 3) * 4;
        *(uint2*)&P_A[r][c4] = make_uint2(0u, 0u);
    }

    // ---- softmax: lane's row l = wid*16 + fr; w values: mf*16 + fq*4 + jj
    const int rl = wid * 16 + fr;
    const float wd = widths[rl], sh = sharps[rl];
    float vals[28];
    float mx = -1e30f;
    #pragma unroll
    for (int mf = 0; mf < 7; ++mf) {
        #pragma unroll
        for (int jj = 0; jj < 4; ++jj) {
            int wv = mf * 16 + fq * 4 + jj;
            int kk = wv - rl;
            float sc = -1e30f;
            if (kk >= 0 && kk <= 48) {
                float rel = fabsf((float)kk - 24.f);
                float msk = sigmoidf_((wd - rel) * sh);
                sc = sacc[mf][jj] * 0.125f - (1.f - msk) * 10000.f;
            }
            vals[mf * 4 + jj] = sc;
            mx = fmaxf(mx, sc);
        }
    }
    mx = fmaxf(mx, __shfl_xor(mx, 16, 64));
    mx = fmaxf(mx, __shfl_xor(mx, 32, 64));
    float sum = 0.f;
    #pragma unroll
    for (int i = 0; i < 28; ++i) {
        float e = __expf(vals[i] - mx);
        vals[i] = e;
        sum += e;
    }
    sum += __shfl_xor(sum, 16, 64);
    sum += __shfl_xor(sum, 32, 64);
    float rs = 1.f / sum;

    // write P rows (own wave only; PV reads only own wave's rows)
    #pragma unroll
    for (int mf = 0; mf < 7; ++mf) {
        unsigned int lo_ = (unsigned int)f2bf(vals[mf * 4 + 0] * rs)
                         | ((unsigned int)f2bf(vals[mf * 4 + 1] * rs) << 16);
        unsigned int hi_ = (unsigned int)f2bf(vals[mf * 4 + 2] * rs)
                         | ((unsigned int)f2bf(vals[mf * 4 + 3] * rs) << 16);
        *(uint2*)&P_A[rl][mf * 16 + fq * 4] = make_uint2(lo_, hi_);
    }

    // ---- PV
    f32x4 oacc[4];
    #pragma unroll
    for (int nf = 0; nf < 4; ++nf) oacc[nf] = (f32x4){0.f, 0.f, 0.f, 0.f};
    #pragma unroll
    for (int ks = 0; ks < 4; ++ks) {
        bf16x8 ap = *(const bf16x8*)&P_A[wid * 16 + fr][ks * 32 + fq * 8];
        #pragma unroll
        for (int nf = 0; nf < 4; ++nf) {
            bf16x8 bv = *(const bf16x8*)&Vt[nf * 16 + fr][ks * 32 + fq * 8];
            oacc[nf] = __builtin_amdgcn_mfma_f32_16x16x32_bf16(ap, bv, oacc[nf], 0, 0, 0);
        }
    }

    const int orow = n0 + wid * 16 + fq * 4;
    #pragma unroll
    for (int nf = 0; nf < 4; ++nf)
        #pragma unroll
        for (int jj = 0; jj < 4; ++jj)
            att[(size_t)(orow + jj) * 512 + h * 64 + nf * 16 + fr] = oacc[nf][jj];
}

// ---------------------------------------------------------------------------
// per-row 1/rms of att (C=512); wave per row
// ---------------------------------------------------------------------------
__global__ __launch_bounds__(256) void inv_rms(
    const float* __restrict__ att, float* __restrict__ inv)
{
    const int n = blockIdx.x * 4 + (threadIdx.x >> 6);
    const int lane = threadIdx.x & 63;
    const float4* p = (const float4*)(att + (size_t)n * 512 + lane * 8);
    float4 a = p[0], c = p[1];
    float ss = a.x*a.x + a.y*a.y + a.z*a.z + a.w*a.w
             + c.x*c.x + c.y*c.y + c.z*c.z + c.w*c.w;
    #pragma unroll
    for (int m = 32; m; m >>= 1) ss += __shfl_xor(ss, m, 64);
    if (lane == 0) inv[n] = rsqrtf(ss * (1.f / 512.f) + 1e-6f);
}

// ---------------------------------------------------------------------------
extern "C" void kernel_launch(void* const* d_in, const int* in_sizes, int n_in,
                              void* d_out, int out_size, void* d_ws, size_t ws_size,
                              hipStream_t stream)
{
    const float* x    = (const float*)d_in[0];
    const float* Wq   = (const float*)d_in[1];
    const float* Wkv  = (const float*)d_in[2];
    const float* Wwin = (const float*)d_in[3];
    const float* bwin = (const float*)d_in[4];
    const float* Wg   = (const float*)d_in[5];
    const float* bg   = (const float*)d_in[6];
    const float* Wout = (const float*)d_in[7];
    const float* qn_w = (const float*)d_in[8];
    const float* kn_w = (const float*)d_in[9];
    const float* on_w = (const float*)d_in[10];
    float* outp = (float*)d_out;

    // workspace layout
    unsigned short* xbf  = (unsigned short*)d_ws;            // 8192*512
    unsigned short* qbB  = xbf  + (size_t)NROW * 512;
    unsigned short* kbB  = qbB  + (size_t)NROW * 512;
    unsigned short* vbB  = kbB  + (size_t)NROW * 512;
    unsigned short* wqb  = vbB  + (size_t)NROW * 512;        // 512*512
    unsigned short* wkvb = wqb  + 512 * 512;                 // 1024*512
    unsigned short* wgb  = wkvb + 1024 * 512;
    unsigned short* woutb= wgb  + 512 * 512;
    unsigned short* wwinb= woutb+ 512 * 512;                 // 128*512
    float* wpb  = (float*)(wwinb + 128 * 512);               // 8192*16 f32
    float* invb = wpb + (size_t)NROW * 16;                   // 8192 f32
    unsigned short* mbf = xbf;                               // reuse xbf after qkv
    float* att = outp;                                       // reuse d_out

    dim3 blk(256);

    conv_bf16<<<dim3(NROW * 512 / 4 / 256), blk, 0, stream>>>(x, xbf, NROW * 512 / 4);
    conv_w5<<<dim3(256, 5), blk, 0, stream>>>(Wq, Wkv, Wg, Wout, wqb, wkvb, wgb, woutb);
    conv_wwin<<<dim3(256), blk, 0, stream>>>(Wwin, wwinb);

    // fused q + kv + wp projections (N = 1664)
    mfma_gemm<10, 128><<<dim3(13, 64), blk, 0, stream>>>(
        xbf, wqb, wkvb, wwinb, wpb, qbB, kbB, vbB, bwin, nullptr, nullptr, nullptr);

    attn_fused<<<dim3(1024), blk, 0, stream>>>(qbB, kbB, vbB, wpb, qn_w, kn_w, att);

    inv_rms<<<dim3(NROW / 4), blk, 0, stream>>>(att, invb);

    // gate-merge -> bf16 merged (rmsnorm applied at read via invb/on_w)
    mfma_gemm<3, 64><<<dim3(4, 128), blk, 0, stream>>>(
        vbB, wgb, nullptr, nullptr, nullptr, mbf, nullptr, nullptr, bg, att, invb, on_w);

    // final projection -> d_out (f32)
    mfma_gemm<0, 64><<<dim3(4, 128), blk, 0, stream>>>(
        mbf, woutb, nullptr, nullptr, outp, nullptr, nullptr, nullptr,
        nullptr, nullptr, nullptr, nullptr);
}